// Round 2
// baseline (155.281 us; speedup 1.0000x reference)
//
#include <hip/hip_runtime.h>

#define NPTS 4096      // points per cloud
#define NB   4         // batch
#define KP   512       // keypoints
#define HUBER_C 0.01f
#define HALF_PTS (NB * NPTS)          // 16384
#define TOT_PTS  (2 * NB * NPTS)      // 32768
#define OSTRIPE 64                    // others per stripe (64 stripes)
#define QCHUNK  1024                  // queries per block (4 per thread)
#define NOC (NPTS / OSTRIPE)          // 64
#define NQC (NPTS / QCHUNK)           // 4
#define GAL_BLOCKS (2 * NB * NQC * NOC)   // 2048
#define NGRP (2 * NB * NQC)               // 32 query-groups
#define NCTRL 35   // ctrl words: [0]=acc f32, [1]=gal f32, [2]=done, [3..34]=grpcnt

typedef float v2f __attribute__((ext_vector_type(2)));

// ws layout:
//   [0,      128 KB)  unsigned minarr[TOT_PTS]
//   [128 KB, +140 B)  ctrl words (see NCTRL)

// Tuning log (MI355X):
//   R3..R7: see git history. Key fact discovered in R8 post-mortem:
//     dur_us is dominated by 2x ~40us 256MiB fillBufferAligned (harness
//     ws re-poison / cache flush) INSIDE the timed window. Our kernels
//     total only ~10-13us. All main-kernel micro-opts were fighting <5us.
//   R8: OSTRIPE 64, LDS-staged o-stripe, prep deleted -> 91.7
//   R9 (this): finalize_kernel deleted. Distributed finalize: per-group
//     (dir,b,qc) counter, 64th stripe-block hubers its 1024 mins (agent-
//     scope atomic loads, cross-XCD safe); global done-counter's last
//     block writes out. 3 dispatches -> 2.

// ---------------- helpers ----------------

__device__ inline void wave_reduce_add_to(float v, float* target) {
    #pragma unroll
    for (int off = 32; off; off >>= 1) v += __shfl_down(v, off, 64);
    if ((threadIdx.x & 63) == 0) atomicAdd(target, v);
}

__device__ inline float huber_f(float x) {
    return (x < HUBER_C) ? 0.5f * x * x
                         : fmaf(HUBER_C, x, -0.5f * HUBER_C * HUBER_C);
}

__device__ inline v2f splat2(float s) { v2f r; r.x = s; r.y = s; return r; }

// ---------------- kernels ----------------

// grid = TOT_PTS/4/256 = 32 blocks. minarr <- +inf, ctrl <- 0.
__global__ __launch_bounds__(256) void init_kernel(
    uint4* __restrict__ minarr4, unsigned* __restrict__ ctrl)
{
    int i = blockIdx.x * 256 + threadIdx.x;      // [0, 8192)
    minarr4[i] = make_uint4(0x7F800000u, 0x7F800000u, 0x7F800000u, 0x7F800000u);
    if (blockIdx.x == 0 && threadIdx.x < NCTRL) ctrl[threadIdx.x] = 0u;
}

// Fused main: [0,knn_blocks) knn; [knn, knn+kp) keypoints; rest = gal
// pairwise-min + distributed finalize + last-block output write.
__global__ __launch_bounds__(256, 6) void main_kernel(
    const float* __restrict__ srcT, const float* __restrict__ tgtT,
    unsigned* __restrict__ minarr,
    const float* __restrict__ skp, const float* __restrict__ tkp,
    const float* __restrict__ R, const float* __restrict__ T,
    const float* __restrict__ aknn, const float* __restrict__ bknn,
    const int* __restrict__ kptr, unsigned* __restrict__ ctrl,
    float* __restrict__ out,
    int knn_blocks, int knn_quads, int total_blocks)
{
    __shared__ float4 olds[OSTRIPE];
    float* accp = (float*)&ctrl[0];
    float* galp = (float*)&ctrl[1];
    unsigned* donep = &ctrl[2];
    unsigned* grpcnt = &ctrl[3];

    const int bid = blockIdx.x;
    const int tid = threadIdx.x;
    const int kp_blocks = (NB * KP) / 256;       // 8
    const int pre = knn_blocks + kp_blocks;

    if (bid >= pre) {
        // ---- global-align pairwise min ----
        const int gb  = bid - pre;             // [0, GAL_BLOCKS)
        const int oc  = gb & (NOC - 1);        // 64 other-stripes of 64
        const int b   = (gb >> 6) & 3;
        const int dir = (gb >> 8) & 1;         // 0: queries=src, 1: queries=tgt
        const int qc  = gb >> 9;               // 4 query-chunks of 1024
        const int grp = gb >> 6;               // [0, NGRP)
        const float* qb = (dir ? tgtT : srcT) + b * 3 * NPTS;
        const float* ob = (dir ? srcT : tgtT) + b * 3 * NPTS;

        // stage o-stripe (xyz + |o|^2) into LDS: one coalesced 64-lane load
        if (tid < OSTRIPE) {
            int oi = oc * OSTRIPE + tid;
            float ox = ob[oi], oy = ob[NPTS + oi], oz = ob[2 * NPTS + oi];
            olds[tid] = make_float4(ox, oy, oz,
                                    fmaf(ox, ox, fmaf(oy, oy, oz * oz)));
        }

        // 4 queries packed as 2 float2 pairs: p in {0,1}, lanes {2p, 2p+1}
        v2f ax2[2], ay2[2], az2[2], mm2[2];
        float qw[4];
        #pragma unroll
        for (int p = 0; p < 2; ++p) {
            int ia = qc * QCHUNK + (2 * p) * 256 + tid;
            int ib = ia + 256;
            float Ax = qb[ia], Ay = qb[NPTS + ia], Az = qb[2 * NPTS + ia];
            float Bx = qb[ib], By = qb[NPTS + ib], Bz = qb[2 * NPTS + ib];
            ax2[p].x = -2.0f * Ax; ax2[p].y = -2.0f * Bx;
            ay2[p].x = -2.0f * Ay; ay2[p].y = -2.0f * By;
            az2[p].x = -2.0f * Az; az2[p].y = -2.0f * Bz;
            qw[2 * p]     = fmaf(Ax, Ax, fmaf(Ay, Ay, Az * Az));
            qw[2 * p + 1] = fmaf(Bx, Bx, fmaf(By, By, Bz * Bz));
            mm2[p].x = 3.0e38f; mm2[p].y = 3.0e38f;
        }
        __syncthreads();

        // per o-pair per q-pair: 6 v_pk_fma_f32 + 2 v_min3_f32
        auto step2 = [&](const float4& u, const float4& v) {
            #pragma unroll
            for (int p = 0; p < 2; ++p) {
                v2f t0 = __builtin_elementwise_fma(splat2(u.x), ax2[p],
                         __builtin_elementwise_fma(splat2(u.y), ay2[p],
                         __builtin_elementwise_fma(splat2(u.z), az2[p], splat2(u.w))));
                v2f t1 = __builtin_elementwise_fma(splat2(v.x), ax2[p],
                         __builtin_elementwise_fma(splat2(v.y), ay2[p],
                         __builtin_elementwise_fma(splat2(v.z), az2[p], splat2(v.w))));
                mm2[p].x = fminf(mm2[p].x, fminf(t0.x, t1.x));   // v_min3_f32
                mm2[p].y = fminf(mm2[p].y, fminf(t0.y, t1.y));
            }
        };

        #pragma unroll 4
        for (int j = 0; j < OSTRIPE; j += 4) {
            float4 o0 = olds[j], o1 = olds[j + 1];
            float4 o2 = olds[j + 2], o3 = olds[j + 3];
            step2(o0, o1);
            step2(o2, o3);
        }

        unsigned* marr = minarr + (dir * NB + b) * NPTS + qc * QCHUNK + tid;
        #pragma unroll
        for (int p = 0; p < 2; ++p) {
            float d0 = fmaxf(qw[2 * p]     + mm2[p].x, 0.0f);  // >=0: atomicMin-safe
            float d1 = fmaxf(qw[2 * p + 1] + mm2[p].y, 0.0f);
            atomicMin(&marr[(2 * p) * 256],     __float_as_uint(d0));
            atomicMin(&marr[(2 * p + 1) * 256], __float_as_uint(d1));
        }

        // ---- distributed finalize: 64th stripe-block of this query-group
        // hubers the group's 1024 mins and adds to galp.
        __syncthreads();   // drain this block's atomicMins (per-wave vmcnt)
        __shared__ unsigned role;
        if (tid == 0) {
            __threadfence();                       // release
            role = (atomicAdd(&grpcnt[grp], 1u) == (unsigned)(NOC - 1));
        }
        __syncthreads();
        if (role) {
            __threadfence();                       // acquire
            const unsigned* gm = minarr + (dir * NB + b) * NPTS + qc * QCHUNK;
            float s = 0.0f;
            #pragma unroll
            for (int k2 = 0; k2 < 4; ++k2) {
                unsigned mv = __hip_atomic_load(&gm[tid + 256 * k2],
                                                __ATOMIC_RELAXED,
                                                __HIP_MEMORY_SCOPE_AGENT);
                s += huber_f(__uint_as_float(mv));
            }
            wave_reduce_add_to(s, galp);
        }
    } else if (bid < knn_blocks) {
        // ---- knn consensus: sum((a-b)^2)/k ----
        int i = bid * 256 + tid;
        float sum = 0.0f;
        if (i < knn_quads) {
            float4 va = ((const float4*)aknn)[i];
            float4 vb = ((const float4*)bknn)[i];
            float dx = va.x - vb.x, dy = va.y - vb.y;
            float dz = va.z - vb.z, dw = va.w - vb.w;
            sum = fmaf(dx, dx, fmaf(dy, dy, fmaf(dz, dz, dw * dw)));
        }
        float scale = 1.0f / (float)(*kptr);
        wave_reduce_add_to(sum * scale, accp);
    } else {
        // ---- keypoints: sum((R@s + t - g)^2) ----
        int i = (bid - knn_blocks) * 256 + tid;    // [0, NB*KP)
        int b = i >> 9;
        int n = i & (KP - 1);
        const float* r = R + b * 9;
        const float* t = T + b * 3;
        const float* s = skp + b * 3 * KP;
        const float* g = tkp + b * 3 * KP;
        float sx = s[n], sy = s[KP + n], sz = s[2 * KP + n];
        float sum = 0.0f;
        #pragma unroll
        for (int d = 0; d < 3; ++d) {
            float v = fmaf(r[d*3+0], sx, fmaf(r[d*3+1], sy, fmaf(r[d*3+2], sz, t[d])))
                      - g[d * KP + n];
            sum = fmaf(v, v, sum);
        }
        wave_reduce_add_to(sum, accp);
    }

    // ---- common tail: last block (globally) writes both outputs ----
    __syncthreads();   // drain all waves' atomic adds/mins for this block
    __shared__ unsigned lastflag;
    if (tid == 0) {
        __threadfence();                           // release
        lastflag = (atomicAdd(donep, 1u) == (unsigned)(total_blocks - 1));
    }
    __syncthreads();
    if (lastflag && tid == 0) {
        __threadfence();                           // acquire
        unsigned a = __hip_atomic_load(&ctrl[0], __ATOMIC_RELAXED,
                                       __HIP_MEMORY_SCOPE_AGENT);
        unsigned g2 = __hip_atomic_load(&ctrl[1], __ATOMIC_RELAXED,
                                        __HIP_MEMORY_SCOPE_AGENT);
        out[0] = __uint_as_float(a);               // neighborhood consensus
        out[1] = __uint_as_float(g2);              // gal
    }
}

// ---------------- fallback (no workspace) ----------------

__global__ void zero_out_kernel(float* __restrict__ out) {
    if (threadIdx.x < 2) out[threadIdx.x] = 0.0f;
}

__global__ __launch_bounds__(256) void gal_direct_kernel(
    const float* __restrict__ srcT, const float* __restrict__ tgtT,
    float* __restrict__ gal_out)
{
    const int dir = blockIdx.y >> 2;
    const int b   = blockIdx.y & 3;
    const float* qb = (dir ? tgtT : srcT) + b * 3 * NPTS;
    const float* ob = (dir ? srcT : tgtT) + b * 3 * NPTS;
    const int qi = blockIdx.x * 256 + threadIdx.x;
    const float qx = qb[qi], qy = qb[NPTS + qi], qz = qb[2 * NPTS + qi];
    float m = 3.0e38f;
    #pragma unroll 4
    for (int j = 0; j < NPTS; ++j) {
        float dx = qx - ob[j], dy = qy - ob[NPTS + j], dz = qz - ob[2 * NPTS + j];
        m = fminf(m, fmaf(dx, dx, fmaf(dy, dy, dz * dz)));
    }
    wave_reduce_add_to(huber_f(m), gal_out);
}

__global__ __launch_bounds__(256) void kp_kernel(
    const float* __restrict__ skp, const float* __restrict__ tkp,
    const float* __restrict__ R, const float* __restrict__ T,
    float* __restrict__ acc)
{
    int i = blockIdx.x * 256 + threadIdx.x;
    int b = i >> 9, n = i & (KP - 1);
    const float* r = R + b * 9;
    const float* t = T + b * 3;
    const float* s = skp + b * 3 * KP;
    const float* g = tkp + b * 3 * KP;
    float sx = s[n], sy = s[KP + n], sz = s[2 * KP + n];
    float sum = 0.0f;
    #pragma unroll
    for (int d = 0; d < 3; ++d) {
        float v = fmaf(r[d*3+0], sx, fmaf(r[d*3+1], sy, fmaf(r[d*3+2], sz, t[d])))
                  - g[d * KP + n];
        sum = fmaf(v, v, sum);
    }
    wave_reduce_add_to(sum, acc);
}

__global__ __launch_bounds__(256) void knn_kernel(
    const float* __restrict__ a, const float* __restrict__ b,
    const int* __restrict__ kptr, float* __restrict__ acc, int quads)
{
    int i = blockIdx.x * 256 + threadIdx.x;
    float sum = 0.0f;
    if (i < quads) {
        float4 va = ((const float4*)a)[i];
        float4 vb = ((const float4*)b)[i];
        float dx = va.x - vb.x, dy = va.y - vb.y;
        float dz = va.z - vb.z, dw = va.w - vb.w;
        sum = fmaf(dx, dx, fmaf(dy, dy, fmaf(dz, dz, dw * dw)));
    }
    float scale = 1.0f / (float)(*kptr);
    wave_reduce_add_to(sum * scale, acc);
}

// ---------------- launch ----------------

extern "C" void kernel_launch(void* const* d_in, const int* in_sizes, int n_in,
                              void* d_out, int out_size, void* d_ws, size_t ws_size,
                              hipStream_t stream) {
    const float* skp  = (const float*)d_in[0];   // (B,3,KP)
    const float* tkp  = (const float*)d_in[1];   // (B,3,KP)
    const float* R    = (const float*)d_in[2];   // (B,3,3)
    const float* T    = (const float*)d_in[3];   // (B,3)
    const float* aknn = (const float*)d_in[4];   // (B,3,KP,K)
    const float* bknn = (const float*)d_in[5];   // (B,3,KP,K)
    const int*   kptr = (const int*)d_in[6];     // scalar k
    const float* srcT = (const float*)d_in[7];   // (B,3,N)
    const float* tgtT = (const float*)d_in[8];   // (B,3,N)
    float* out = (float*)d_out;

    const int knn_quads  = in_sizes[4] / 4;                 // 49152
    const int knn_blocks = (knn_quads + 255) / 256;         // 192
    const int kp_blocks  = (NB * KP + 255) / 256;           // 8

    const size_t min_bytes = (size_t)TOT_PTS * 4;           // 128 KB
    const size_t ws_need   = min_bytes + NCTRL * 4;
    if (ws_size >= ws_need) {
        unsigned* minarr = (unsigned*)d_ws;
        unsigned* ctrl   = (unsigned*)((char*)d_ws + min_bytes);
        const int total  = knn_blocks + kp_blocks + GAL_BLOCKS;
        init_kernel<<<TOT_PTS / 4 / 256, 256, 0, stream>>>((uint4*)minarr, ctrl);
        main_kernel<<<total, 256, 0, stream>>>(
            srcT, tgtT, minarr, skp, tkp, R, T, aknn, bknn, kptr, ctrl, out,
            knn_blocks, knn_quads, total);
    } else {
        zero_out_kernel<<<1, 64, 0, stream>>>(out);
        gal_direct_kernel<<<dim3(NPTS / 256, 2 * NB), 256, 0, stream>>>(srcT, tgtT, out + 1);
        kp_kernel<<<kp_blocks, 256, 0, stream>>>(skp, tkp, R, T, out);
        knn_kernel<<<knn_blocks, 256, 0, stream>>>(aknn, bknn, kptr, out, knn_quads);
    }
}

// Round 3
// 122.086 us; speedup vs baseline: 1.2719x; 1.2719x over previous
//
#include <hip/hip_runtime.h>

#define NPTS 4096      // points per cloud
#define NB   4         // batch
#define KP   512       // keypoints
#define HUBER_C 0.01f
#define HALF_PTS (NB * NPTS)          // 16384
#define TOT_PTS  (2 * NB * NPTS)      // 32768
#define OSTRIPE 64                    // others per stripe (64 stripes)
#define QCHUNK  1024                  // queries per block (4 per thread)
#define NOC (NPTS / OSTRIPE)          // 64
#define NQC (NPTS / QCHUNK)           // 4
#define GAL_BLOCKS (2 * NB * NQC * NOC)   // 2048
#define NGRP (2 * NB * NQC)               // 32 query-groups
#define NCTRL 35   // ctrl words: [0]=acc f32, [1]=gal f32, [2]=done, [3..34]=grpcnt

typedef float v2f __attribute__((ext_vector_type(2)));

// ws layout:
//   [0,      128 KB)  unsigned minarr[TOT_PTS]
//   [128 KB, +140 B)  ctrl words (see NCTRL)

// Tuning log (MI355X):
//   R3..R7: see git history. R8 post-mortem: dur_us window contains 2x
//     ~40us 256MiB fillBufferAligned (harness ws re-poison). Our kernels
//     total only ~10-13us of the ~92us.
//   R8: OSTRIPE 64, LDS-staged o-stripe, prep deleted -> 91.7
//   R9: distributed finalize w/ __threadfence() -> 155.3 REGRESSION.
//     main_kernel=93us, VALUBusy 9%, HBM 1.5%: __threadfence on gfx950
//     = buffer_wbl2/buffer_inv (L2 writeback/inv); ~9K of them serialized
//     the memory system. LESSON: never per-block device fences on CDNA4.
//   R10 (this): R9 minus ALL fences. Device-scope atomic RMWs complete at
//     the cross-XCD coherent point; __syncthreads drains vmcnt before the
//     counter bump; readers use sc1 (AGENT) atomic loads. No cache
//     maintenance needed.

// ---------------- helpers ----------------

__device__ inline void wave_reduce_add_to(float v, float* target) {
    #pragma unroll
    for (int off = 32; off; off >>= 1) v += __shfl_down(v, off, 64);
    if ((threadIdx.x & 63) == 0) atomicAdd(target, v);
}

__device__ inline float huber_f(float x) {
    return (x < HUBER_C) ? 0.5f * x * x
                         : fmaf(HUBER_C, x, -0.5f * HUBER_C * HUBER_C);
}

__device__ inline v2f splat2(float s) { v2f r; r.x = s; r.y = s; return r; }

// ---------------- kernels ----------------

// grid = TOT_PTS/4/256 = 32 blocks. minarr <- +inf, ctrl <- 0.
__global__ __launch_bounds__(256) void init_kernel(
    uint4* __restrict__ minarr4, unsigned* __restrict__ ctrl)
{
    int i = blockIdx.x * 256 + threadIdx.x;      // [0, 8192)
    minarr4[i] = make_uint4(0x7F800000u, 0x7F800000u, 0x7F800000u, 0x7F800000u);
    if (blockIdx.x == 0 && threadIdx.x < NCTRL) ctrl[threadIdx.x] = 0u;
}

// Fused main: [0,knn_blocks) knn; [knn, knn+kp) keypoints; rest = gal
// pairwise-min + distributed finalize + last-block output write.
__global__ __launch_bounds__(256, 6) void main_kernel(
    const float* __restrict__ srcT, const float* __restrict__ tgtT,
    unsigned* __restrict__ minarr,
    const float* __restrict__ skp, const float* __restrict__ tkp,
    const float* __restrict__ R, const float* __restrict__ T,
    const float* __restrict__ aknn, const float* __restrict__ bknn,
    const int* __restrict__ kptr, unsigned* __restrict__ ctrl,
    float* __restrict__ out,
    int knn_blocks, int knn_quads, int total_blocks)
{
    __shared__ float4 olds[OSTRIPE];
    float* accp = (float*)&ctrl[0];
    float* galp = (float*)&ctrl[1];
    unsigned* donep = &ctrl[2];
    unsigned* grpcnt = &ctrl[3];

    const int bid = blockIdx.x;
    const int tid = threadIdx.x;
    const int kp_blocks = (NB * KP) / 256;       // 8
    const int pre = knn_blocks + kp_blocks;

    if (bid >= pre) {
        // ---- global-align pairwise min ----
        const int gb  = bid - pre;             // [0, GAL_BLOCKS)
        const int oc  = gb & (NOC - 1);        // 64 other-stripes of 64
        const int b   = (gb >> 6) & 3;
        const int dir = (gb >> 8) & 1;         // 0: queries=src, 1: queries=tgt
        const int qc  = gb >> 9;               // 4 query-chunks of 1024
        const int grp = gb >> 6;               // [0, NGRP)
        const float* qb = (dir ? tgtT : srcT) + b * 3 * NPTS;
        const float* ob = (dir ? srcT : tgtT) + b * 3 * NPTS;

        // stage o-stripe (xyz + |o|^2) into LDS: one coalesced 64-lane load
        if (tid < OSTRIPE) {
            int oi = oc * OSTRIPE + tid;
            float ox = ob[oi], oy = ob[NPTS + oi], oz = ob[2 * NPTS + oi];
            olds[tid] = make_float4(ox, oy, oz,
                                    fmaf(ox, ox, fmaf(oy, oy, oz * oz)));
        }

        // 4 queries packed as 2 float2 pairs: p in {0,1}, lanes {2p, 2p+1}
        v2f ax2[2], ay2[2], az2[2], mm2[2];
        float qw[4];
        #pragma unroll
        for (int p = 0; p < 2; ++p) {
            int ia = qc * QCHUNK + (2 * p) * 256 + tid;
            int ib = ia + 256;
            float Ax = qb[ia], Ay = qb[NPTS + ia], Az = qb[2 * NPTS + ia];
            float Bx = qb[ib], By = qb[NPTS + ib], Bz = qb[2 * NPTS + ib];
            ax2[p].x = -2.0f * Ax; ax2[p].y = -2.0f * Bx;
            ay2[p].x = -2.0f * Ay; ay2[p].y = -2.0f * By;
            az2[p].x = -2.0f * Az; az2[p].y = -2.0f * Bz;
            qw[2 * p]     = fmaf(Ax, Ax, fmaf(Ay, Ay, Az * Az));
            qw[2 * p + 1] = fmaf(Bx, Bx, fmaf(By, By, Bz * Bz));
            mm2[p].x = 3.0e38f; mm2[p].y = 3.0e38f;
        }
        __syncthreads();

        // per o-pair per q-pair: 6 v_pk_fma_f32 + 2 v_min3_f32
        auto step2 = [&](const float4& u, const float4& v) {
            #pragma unroll
            for (int p = 0; p < 2; ++p) {
                v2f t0 = __builtin_elementwise_fma(splat2(u.x), ax2[p],
                         __builtin_elementwise_fma(splat2(u.y), ay2[p],
                         __builtin_elementwise_fma(splat2(u.z), az2[p], splat2(u.w))));
                v2f t1 = __builtin_elementwise_fma(splat2(v.x), ax2[p],
                         __builtin_elementwise_fma(splat2(v.y), ay2[p],
                         __builtin_elementwise_fma(splat2(v.z), az2[p], splat2(v.w))));
                mm2[p].x = fminf(mm2[p].x, fminf(t0.x, t1.x));   // v_min3_f32
                mm2[p].y = fminf(mm2[p].y, fminf(t0.y, t1.y));
            }
        };

        #pragma unroll 4
        for (int j = 0; j < OSTRIPE; j += 4) {
            float4 o0 = olds[j], o1 = olds[j + 1];
            float4 o2 = olds[j + 2], o3 = olds[j + 3];
            step2(o0, o1);
            step2(o2, o3);
        }

        unsigned* marr = minarr + (dir * NB + b) * NPTS + qc * QCHUNK + tid;
        #pragma unroll
        for (int p = 0; p < 2; ++p) {
            float d0 = fmaxf(qw[2 * p]     + mm2[p].x, 0.0f);  // >=0: atomicMin-safe
            float d1 = fmaxf(qw[2 * p + 1] + mm2[p].y, 0.0f);
            atomicMin(&marr[(2 * p) * 256],     __float_as_uint(d0));
            atomicMin(&marr[(2 * p + 1) * 256], __float_as_uint(d1));
        }

        // ---- distributed finalize: 64th stripe-block of this query-group
        // hubers the group's 1024 mins and adds to galp. NO FENCES: the
        // atomicMins are device-scope RMWs (coherent point) and each wave
        // drained vmcnt at the barrier before tid0 bumps the counter.
        __syncthreads();
        __shared__ unsigned role;
        if (tid == 0)
            role = (atomicAdd(&grpcnt[grp], 1u) == (unsigned)(NOC - 1));
        __syncthreads();
        if (role) {
            const unsigned* gm = minarr + (dir * NB + b) * NPTS + qc * QCHUNK;
            float s = 0.0f;
            #pragma unroll
            for (int k2 = 0; k2 < 4; ++k2) {
                unsigned mv = __hip_atomic_load(&gm[tid + 256 * k2],
                                                __ATOMIC_RELAXED,
                                                __HIP_MEMORY_SCOPE_AGENT);
                s += huber_f(__uint_as_float(mv));
            }
            wave_reduce_add_to(s, galp);
        }
    } else if (bid < knn_blocks) {
        // ---- knn consensus: sum((a-b)^2)/k ----
        int i = bid * 256 + tid;
        float sum = 0.0f;
        if (i < knn_quads) {
            float4 va = ((const float4*)aknn)[i];
            float4 vb = ((const float4*)bknn)[i];
            float dx = va.x - vb.x, dy = va.y - vb.y;
            float dz = va.z - vb.z, dw = va.w - vb.w;
            sum = fmaf(dx, dx, fmaf(dy, dy, fmaf(dz, dz, dw * dw)));
        }
        float scale = 1.0f / (float)(*kptr);
        wave_reduce_add_to(sum * scale, accp);
    } else {
        // ---- keypoints: sum((R@s + t - g)^2) ----
        int i = (bid - knn_blocks) * 256 + tid;    // [0, NB*KP)
        int b = i >> 9;
        int n = i & (KP - 1);
        const float* r = R + b * 9;
        const float* t = T + b * 3;
        const float* s = skp + b * 3 * KP;
        const float* g = tkp + b * 3 * KP;
        float sx = s[n], sy = s[KP + n], sz = s[2 * KP + n];
        float sum = 0.0f;
        #pragma unroll
        for (int d = 0; d < 3; ++d) {
            float v = fmaf(r[d*3+0], sx, fmaf(r[d*3+1], sy, fmaf(r[d*3+2], sz, t[d])))
                      - g[d * KP + n];
            sum = fmaf(v, v, sum);
        }
        wave_reduce_add_to(sum, accp);
    }

    // ---- common tail: last block (globally) writes both outputs ----
    __syncthreads();   // drain all waves' atomic adds/mins for this block
    __shared__ unsigned lastflag;
    if (tid == 0)
        lastflag = (atomicAdd(donep, 1u) == (unsigned)(total_blocks - 1));
    __syncthreads();
    if (lastflag && tid == 0) {
        unsigned a = __hip_atomic_load(&ctrl[0], __ATOMIC_RELAXED,
                                       __HIP_MEMORY_SCOPE_AGENT);
        unsigned g2 = __hip_atomic_load(&ctrl[1], __ATOMIC_RELAXED,
                                        __HIP_MEMORY_SCOPE_AGENT);
        out[0] = __uint_as_float(a);               // neighborhood consensus
        out[1] = __uint_as_float(g2);              // gal
    }
}

// ---------------- fallback (no workspace) ----------------

__global__ void zero_out_kernel(float* __restrict__ out) {
    if (threadIdx.x < 2) out[threadIdx.x] = 0.0f;
}

__global__ __launch_bounds__(256) void gal_direct_kernel(
    const float* __restrict__ srcT, const float* __restrict__ tgtT,
    float* __restrict__ gal_out)
{
    const int dir = blockIdx.y >> 2;
    const int b   = blockIdx.y & 3;
    const float* qb = (dir ? tgtT : srcT) + b * 3 * NPTS;
    const float* ob = (dir ? srcT : tgtT) + b * 3 * NPTS;
    const int qi = blockIdx.x * 256 + threadIdx.x;
    const float qx = qb[qi], qy = qb[NPTS + qi], qz = qb[2 * NPTS + qi];
    float m = 3.0e38f;
    #pragma unroll 4
    for (int j = 0; j < NPTS; ++j) {
        float dx = qx - ob[j], dy = qy - ob[NPTS + j], dz = qz - ob[2 * NPTS + j];
        m = fminf(m, fmaf(dx, dx, fmaf(dy, dy, dz * dz)));
    }
    wave_reduce_add_to(huber_f(m), gal_out);
}

__global__ __launch_bounds__(256) void kp_kernel(
    const float* __restrict__ skp, const float* __restrict__ tkp,
    const float* __restrict__ R, const float* __restrict__ T,
    float* __restrict__ acc)
{
    int i = blockIdx.x * 256 + threadIdx.x;
    int b = i >> 9, n = i & (KP - 1);
    const float* r = R + b * 9;
    const float* t = T + b * 3;
    const float* s = skp + b * 3 * KP;
    const float* g = tkp + b * 3 * KP;
    float sx = s[n], sy = s[KP + n], sz = s[2 * KP + n];
    float sum = 0.0f;
    #pragma unroll
    for (int d = 0; d < 3; ++d) {
        float v = fmaf(r[d*3+0], sx, fmaf(r[d*3+1], sy, fmaf(r[d*3+2], sz, t[d])))
                  - g[d * KP + n];
        sum = fmaf(v, v, sum);
    }
    wave_reduce_add_to(sum, acc);
}

__global__ __launch_bounds__(256) void knn_kernel(
    const float* __restrict__ a, const float* __restrict__ b,
    const int* __restrict__ kptr, float* __restrict__ acc, int quads)
{
    int i = blockIdx.x * 256 + threadIdx.x;
    float sum = 0.0f;
    if (i < quads) {
        float4 va = ((const float4*)a)[i];
        float4 vb = ((const float4*)b)[i];
        float dx = va.x - vb.x, dy = va.y - vb.y;
        float dz = va.z - vb.z, dw = va.w - vb.w;
        sum = fmaf(dx, dx, fmaf(dy, dy, fmaf(dz, dz, dw * dw)));
    }
    float scale = 1.0f / (float)(*kptr);
    wave_reduce_add_to(sum * scale, acc);
}

// ---------------- launch ----------------

extern "C" void kernel_launch(void* const* d_in, const int* in_sizes, int n_in,
                              void* d_out, int out_size, void* d_ws, size_t ws_size,
                              hipStream_t stream) {
    const float* skp  = (const float*)d_in[0];   // (B,3,KP)
    const float* tkp  = (const float*)d_in[1];   // (B,3,KP)
    const float* R    = (const float*)d_in[2];   // (B,3,3)
    const float* T    = (const float*)d_in[3];   // (B,3)
    const float* aknn = (const float*)d_in[4];   // (B,3,KP,K)
    const float* bknn = (const float*)d_in[5];   // (B,3,KP,K)
    const int*   kptr = (const int*)d_in[6];     // scalar k
    const float* srcT = (const float*)d_in[7];   // (B,3,N)
    const float* tgtT = (const float*)d_in[8];   // (B,3,N)
    float* out = (float*)d_out;

    const int knn_quads  = in_sizes[4] / 4;                 // 49152
    const int knn_blocks = (knn_quads + 255) / 256;         // 192
    const int kp_blocks  = (NB * KP + 255) / 256;           // 8

    const size_t min_bytes = (size_t)TOT_PTS * 4;           // 128 KB
    const size_t ws_need   = min_bytes + NCTRL * 4;
    if (ws_size >= ws_need) {
        unsigned* minarr = (unsigned*)d_ws;
        unsigned* ctrl   = (unsigned*)((char*)d_ws + min_bytes);
        const int total  = knn_blocks + kp_blocks + GAL_BLOCKS;
        init_kernel<<<TOT_PTS / 4 / 256, 256, 0, stream>>>((uint4*)minarr, ctrl);
        main_kernel<<<total, 256, 0, stream>>>(
            srcT, tgtT, minarr, skp, tkp, R, T, aknn, bknn, kptr, ctrl, out,
            knn_blocks, knn_quads, total);
    } else {
        zero_out_kernel<<<1, 64, 0, stream>>>(out);
        gal_direct_kernel<<<dim3(NPTS / 256, 2 * NB), 256, 0, stream>>>(srcT, tgtT, out + 1);
        kp_kernel<<<kp_blocks, 256, 0, stream>>>(skp, tkp, R, T, out);
        knn_kernel<<<knn_blocks, 256, 0, stream>>>(aknn, bknn, kptr, out, knn_quads);
    }
}

// Round 4
// 95.042 us; speedup vs baseline: 1.6338x; 1.2845x over previous
//
#include <hip/hip_runtime.h>

#define NPTS 4096      // points per cloud
#define NB   4         // batch
#define KP   512       // keypoints
#define HUBER_C 0.01f
#define QCHUNK 128                 // queries per gal block
#define NQC (NPTS / QCHUNK)        // 32 query chunks per (dir,b)
#define GAL_BLOCKS (2 * NB * NQC)  // 256
#define NPK (NPTS / 2)             // 2048 o-pair packs

typedef float v2f __attribute__((ext_vector_type(2)));

// Tuning log (MI355X):
//   R3..R7: see git history.
//   R8: OSTRIPE 64, LDS o-stripe, prep deleted -> 91.7
//   R9: distributed finalize w/ __threadfence() -> 155.3. LESSON: a
//     __threadfence on gfx950 = buffer_wbl2/inv (L2 writeback); ~9K of
//     them serialized the memory system (main 93us, VALUBusy 9%).
//   R10: fences removed -> 122.1, main 53.7us, VALUBusy 15.6%, WRITE
//     8.36 MB = 2M atomicMin x 4B at ~200 GB/s effective. DIAGNOSIS: the
//     device-scope atomicMin stream (coherent-point RMW throughput +
//     same-line ctrl contention) IS the kernel cost; distance math is
//     ~4us. Prior session's "R5: atomics NOT the issue" held atomic
//     count constant and couldn't see it.
//   R11 (this): no cross-block min at all. Each gal block owns 128
//     queries, stages ALL 4096 others in LDS (64KB pair-packed), scan
//     split in half across wave-pairs, register min -> huber -> block
//     reduce -> ONE atomicAdd/block straight into out[]. minarr, its
//     init, 2M atomicMins, grpcnt, done-counter: all deleted. ws unused.

// ---------------- helpers ----------------

__device__ inline float huber_f(float x) {
    return (x < HUBER_C) ? 0.5f * x * x
                         : fmaf(HUBER_C, x, -0.5f * HUBER_C * HUBER_C);
}

__device__ inline v2f splat2(float s) { v2f r; r.x = s; r.y = s; return r; }

// ---------------- kernels ----------------

__global__ void init_kernel(float* __restrict__ out) {
    if (threadIdx.x < 2) out[threadIdx.x] = 0.0f;
}

// Fused: [0,knn_blocks) knn; [knn, knn+kp) keypoints; rest = gal.
// Every block ends with one atomicAdd into out[0] or out[1].
__global__ __launch_bounds__(256) void main_kernel(
    const float* __restrict__ srcT, const float* __restrict__ tgtT,
    const float* __restrict__ skp, const float* __restrict__ tkp,
    const float* __restrict__ R, const float* __restrict__ T,
    const float* __restrict__ aknn, const float* __restrict__ bknn,
    const int* __restrict__ kptr, float* __restrict__ out,
    int knn_blocks, int knn_quads)
{
    __shared__ float4 lds_a[NPK];      // {x0,x1,y0,y1} per o-pair
    __shared__ float4 lds_b[NPK];      // {z0,z1,w0,w1} per o-pair
    __shared__ float pmin[QCHUNK];     // upper-half partial mins
    __shared__ float red[4];

    const int bid = blockIdx.x;
    const int tid = threadIdx.x;
    const int kp_blocks = (NB * KP) / 256;    // 8
    const int pre = knn_blocks + kp_blocks;   // 200
    float contrib = 0.0f;
    float* target;

    if (bid >= pre) {
        // ---- global-align: full o-scan per query, min in registers ----
        const int gb  = bid - pre;            // [0, 256)
        const int qc  = gb & (NQC - 1);
        const int b   = (gb >> 5) & 3;
        const int dir = gb >> 7;              // 0: queries=src, 1: queries=tgt
        const float* qb = (dir ? tgtT : srcT) + b * 3 * NPTS;
        const float* ob = (dir ? srcT : tgtT) + b * 3 * NPTS;

        // stage whole other-cloud into LDS, pair-packed for pk_fma
        #pragma unroll
        for (int idx = tid; idx < NPK; idx += 256) {
            int j = 2 * idx;
            float2 X = *(const float2*)(ob + j);
            float2 Y = *(const float2*)(ob + NPTS + j);
            float2 Z = *(const float2*)(ob + 2 * NPTS + j);
            float w0 = fmaf(X.x, X.x, fmaf(Y.x, Y.x, Z.x * Z.x));
            float w1 = fmaf(X.y, X.y, fmaf(Y.y, Y.y, Z.y * Z.y));
            lds_a[idx] = make_float4(X.x, X.y, Y.x, Y.y);
            lds_b[idx] = make_float4(Z.x, Z.y, w0, w1);
        }

        // one query per thread; halves of the block scan halves of o
        const int q = qc * QCHUNK + (tid & (QCHUNK - 1));
        const float qx = qb[q], qy = qb[NPTS + q], qz = qb[2 * NPTS + q];
        const float ax = -2.0f * qx, ay = -2.0f * qy, az = -2.0f * qz;
        const float qw2 = fmaf(qx, qx, fmaf(qy, qy, qz * qz));
        const int h = tid >> 7;               // 0 or 1 (wave-uniform)
        __syncthreads();

        const float4* la = lds_a + h * (NPK / 2);
        const float4* lb = lds_b + h * (NPK / 2);
        v2f mm; mm.x = 3.0e38f; mm.y = 3.0e38f;
        auto pack_step = [&](const float4& A, const float4& B) -> v2f {
            v2f X, Y, Z, W;
            X.x = A.x; X.y = A.y; Y.x = A.z; Y.y = A.w;
            Z.x = B.x; Z.y = B.y; W.x = B.z; W.y = B.w;
            return __builtin_elementwise_fma(X, splat2(ax),
                   __builtin_elementwise_fma(Y, splat2(ay),
                   __builtin_elementwise_fma(Z, splat2(az), W)));
        };
        // per 2 packs (4 o-points): 6 v_pk_fma_f32 + 2 v_min3_f32
        #pragma unroll 4
        for (int p = 0; p < NPK / 2; p += 2) {
            v2f t0 = pack_step(la[p],     lb[p]);
            v2f t1 = pack_step(la[p + 1], lb[p + 1]);
            mm.x = fminf(mm.x, fminf(t0.x, t1.x));
            mm.y = fminf(mm.y, fminf(t0.y, t1.y));
        }
        float m = fminf(mm.x, mm.y);
        if (h) pmin[tid & (QCHUNK - 1)] = m;
        __syncthreads();
        if (!h) contrib = huber_f(fminf(m, pmin[tid]) + qw2);
        target = out + 1;
    } else if (bid < knn_blocks) {
        // ---- knn consensus: sum((a-b)^2)/k ----
        int i = bid * 256 + tid;
        if (i < knn_quads) {
            float4 va = ((const float4*)aknn)[i];
            float4 vb = ((const float4*)bknn)[i];
            float dx = va.x - vb.x, dy = va.y - vb.y;
            float dz = va.z - vb.z, dw = va.w - vb.w;
            contrib = fmaf(dx, dx, fmaf(dy, dy, fmaf(dz, dz, dw * dw)));
        }
        contrib *= 1.0f / (float)(*kptr);
        target = out;
    } else {
        // ---- keypoints: sum((R@s + t - g)^2) ----
        int i = (bid - knn_blocks) * 256 + tid;   // [0, NB*KP)
        int b = i >> 9;
        int n = i & (KP - 1);
        const float* r = R + b * 9;
        const float* t = T + b * 3;
        const float* s = skp + b * 3 * KP;
        const float* g = tkp + b * 3 * KP;
        float sx = s[n], sy = s[KP + n], sz = s[2 * KP + n];
        #pragma unroll
        for (int d = 0; d < 3; ++d) {
            float v = fmaf(r[d*3+0], sx, fmaf(r[d*3+1], sy, fmaf(r[d*3+2], sz, t[d])))
                      - g[d * KP + n];
            contrib = fmaf(v, v, contrib);
        }
        target = out;
    }

    // ---- block-wide sum -> single atomicAdd ----
    float v = contrib;
    #pragma unroll
    for (int off = 32; off; off >>= 1) v += __shfl_down(v, off, 64);
    if ((tid & 63) == 0) red[tid >> 6] = v;
    __syncthreads();
    if (tid == 0)
        atomicAdd(target, red[0] + red[1] + red[2] + red[3]);
}

// ---------------- launch ----------------

extern "C" void kernel_launch(void* const* d_in, const int* in_sizes, int n_in,
                              void* d_out, int out_size, void* d_ws, size_t ws_size,
                              hipStream_t stream) {
    const float* skp  = (const float*)d_in[0];   // (B,3,KP)
    const float* tkp  = (const float*)d_in[1];   // (B,3,KP)
    const float* R    = (const float*)d_in[2];   // (B,3,3)
    const float* T    = (const float*)d_in[3];   // (B,3)
    const float* aknn = (const float*)d_in[4];   // (B,3,KP,K)
    const float* bknn = (const float*)d_in[5];   // (B,3,KP,K)
    const int*   kptr = (const int*)d_in[6];     // scalar k
    const float* srcT = (const float*)d_in[7];   // (B,3,N)
    const float* tgtT = (const float*)d_in[8];   // (B,3,N)
    float* out = (float*)d_out;

    const int knn_quads  = in_sizes[4] / 4;                 // 49152
    const int knn_blocks = (knn_quads + 255) / 256;         // 192
    const int kp_blocks  = (NB * KP + 255) / 256;           // 8
    const int total      = knn_blocks + kp_blocks + GAL_BLOCKS;   // 456

    init_kernel<<<1, 64, 0, stream>>>(out);
    main_kernel<<<total, 256, 0, stream>>>(
        srcT, tgtT, skp, tkp, R, T, aknn, bknn, kptr, out,
        knn_blocks, knn_quads);
}

// Round 5
// 85.230 us; speedup vs baseline: 1.8219x; 1.1151x over previous
//
#include <hip/hip_runtime.h>

#define NPTS 4096      // points per cloud
#define NB   4         // batch
#define KP   512       // keypoints
#define HUBER_C 0.01f
#define QCHUNK 128                 // queries per gal block
#define NQC (NPTS / QCHUNK)        // 32
#define GAL_BLOCKS (2 * NB * NQC)  // 256
#define NPK (NPTS / 2)             // 2048 o-pair packs
#define NOG 16                     // o-groups per block (16 threads each)
#define PKG (NPK / NOG)            // 128 packs per group
#define QPT 8                      // queries per thread
#define LDA_STRIDE (PKG + 1)       // +16B/group: 4-bank phase shift -> no conflict
#define PMIN_STRIDE (QCHUNK + 4)   // same trick for the partial-min array

typedef float v2f __attribute__((ext_vector_type(2)));

// Tuning log (MI355X):
//   R8: OSTRIPE 64, LDS o-stripe -> 91.7 (window: ~68us fixed harness
//     fills + our ~23us).
//   R9: distributed finalize w/ __threadfence() -> 155.3. LESSON:
//     __threadfence on gfx950 = buffer_wbl2/inv; ~9K of them serialized
//     the memory system (main 93us, VALUBusy 9%).
//   R10: fences removed -> 122.1, main 53.7us. DIAGNOSIS: 2M device-scope
//     atomicMin stream = the cost (WRITE 8.4MB @ ~200GB/s effective).
//   R11: per-block full scan, register min, 1 atomicAdd/block -> 95.0,
//     main ~27us. DIAGNOSIS: LDS-ISSUE BOUND: 1 query/thread = 2.1M
//     ds_read_b128 kernel-wide (~4+cyc each on the per-CU DS pipe).
//   R12 (this): 8 queries/thread. Per pack: 2 DS reads feed 16 dists.
//     DS instrs 2.1M -> 262K (8x); VALU at ~3us floor; padded group
//     offsets keep the 4-address wave reads bank-conflict-free.

// ---------------- helpers ----------------

__device__ inline float huber_f(float x) {
    return (x < HUBER_C) ? 0.5f * x * x
                         : fmaf(HUBER_C, x, -0.5f * HUBER_C * HUBER_C);
}

__device__ inline v2f splat2(float s) { v2f r; r.x = s; r.y = s; return r; }

// ---------------- kernels ----------------

__global__ void init_kernel(float* __restrict__ out) {
    if (threadIdx.x < 2) out[threadIdx.x] = 0.0f;
}

// Fused: [0,GAL_BLOCKS) gal; then knn; then kp.
// Every block ends with one atomicAdd into out[0] or out[1].
__global__ __launch_bounds__(256) void main_kernel(
    const float* __restrict__ srcT, const float* __restrict__ tgtT,
    const float* __restrict__ skp, const float* __restrict__ tkp,
    const float* __restrict__ R, const float* __restrict__ T,
    const float* __restrict__ aknn, const float* __restrict__ bknn,
    const int* __restrict__ kptr, float* __restrict__ out,
    int knn_blocks, int knn_quads)
{
    __shared__ float4 lds_a[NOG * LDA_STRIDE];   // {x0,x1,y0,y1} per o-pair
    __shared__ float4 lds_b[NOG * LDA_STRIDE];   // {z0,z1,w0,w1} per o-pair
    __shared__ float pminl[NOG * PMIN_STRIDE];   // per-group partial mins (+qw)
    __shared__ float red[4];

    const int bid = blockIdx.x;
    const int tid = threadIdx.x;
    float contrib = 0.0f;
    float* target;

    if (bid < GAL_BLOCKS) {
        // ---- global-align: 128 queries/block, 16-way o-split ----
        const int qc  = bid & (NQC - 1);
        const int b   = (bid >> 5) & 3;
        const int dir = bid >> 7;             // 0: queries=src, 1: queries=tgt
        const float* qb = (dir ? tgtT : srcT) + b * 3 * NPTS;
        const float* ob = (dir ? srcT : tgtT) + b * 3 * NPTS;

        // stage whole other-cloud into LDS, pair-packed, group-padded
        #pragma unroll
        for (int k = 0; k < NPK / 256; ++k) {          // 8 iters
            int idx = tid + k * 256;
            int j = 2 * idx;
            float2 X = *(const float2*)(ob + j);
            float2 Y = *(const float2*)(ob + NPTS + j);
            float2 Z = *(const float2*)(ob + 2 * NPTS + j);
            float w0 = fmaf(X.x, X.x, fmaf(Y.x, Y.x, Z.x * Z.x));
            float w1 = fmaf(X.y, X.y, fmaf(Y.y, Y.y, Z.y * Z.y));
            int li = idx + (idx >> 7);                 // group-padded index
            lds_a[li] = make_float4(X.x, X.y, Y.x, Y.y);
            lds_b[li] = make_float4(Z.x, Z.y, w0, w1);
        }

        // 8 queries per thread in registers (threads t and t^16.. share
        // queries, scan different o-groups)
        const int ql0 = tid & 15;
        const int og  = tid >> 4;
        float ax[QPT], ay[QPT], az[QPT], qw[QPT];
        v2f mm[QPT];
        #pragma unroll
        for (int j = 0; j < QPT; ++j) {
            int q = qc * QCHUNK + ql0 + 16 * j;
            float x = qb[q], y = qb[NPTS + q], z = qb[2 * NPTS + q];
            ax[j] = -2.0f * x; ay[j] = -2.0f * y; az[j] = -2.0f * z;
            qw[j] = fmaf(x, x, fmaf(y, y, z * z));
            mm[j].x = 3.0e38f; mm[j].y = 3.0e38f;
        }
        __syncthreads();

        // inner scan: per pack, 2 ds_read_b128 feed 8q x 2o = 16 dists
        const float4* la = lds_a + og * LDA_STRIDE;
        const float4* lb = lds_b + og * LDA_STRIDE;
        #pragma unroll 4
        for (int p = 0; p < PKG; ++p) {
            float4 A = la[p], B = lb[p];
            v2f X, Y, Z, W;
            X.x = A.x; X.y = A.y; Y.x = A.z; Y.y = A.w;
            Z.x = B.x; Z.y = B.y; W.x = B.z; W.y = B.w;
            #pragma unroll
            for (int j = 0; j < QPT; ++j) {
                v2f t = __builtin_elementwise_fma(X, splat2(ax[j]),
                        __builtin_elementwise_fma(Y, splat2(ay[j]),
                        __builtin_elementwise_fma(Z, splat2(az[j]), W)));
                mm[j] = __builtin_elementwise_min(mm[j], t);
            }
        }

        // partial min (+qw: exact, min commutes with constant add)
        #pragma unroll
        for (int j = 0; j < QPT; ++j)
            pminl[og * PMIN_STRIDE + ql0 + 16 * j] =
                fminf(mm[j].x, mm[j].y) + qw[j];
        __syncthreads();

        if (tid < QCHUNK) {
            float m = 3.0e38f;
            #pragma unroll
            for (int g = 0; g < NOG; ++g)
                m = fminf(m, pminl[g * PMIN_STRIDE + tid]);
            contrib = huber_f(m);
        }
        target = out + 1;
    } else if (bid < GAL_BLOCKS + knn_blocks) {
        // ---- knn consensus: sum((a-b)^2)/k ----
        int i = (bid - GAL_BLOCKS) * 256 + tid;
        if (i < knn_quads) {
            float4 va = ((const float4*)aknn)[i];
            float4 vb = ((const float4*)bknn)[i];
            float dx = va.x - vb.x, dy = va.y - vb.y;
            float dz = va.z - vb.z, dw = va.w - vb.w;
            contrib = fmaf(dx, dx, fmaf(dy, dy, fmaf(dz, dz, dw * dw)));
        }
        contrib *= 1.0f / (float)(*kptr);
        target = out;
    } else {
        // ---- keypoints: sum((R@s + t - g)^2) ----
        int i = (bid - GAL_BLOCKS - knn_blocks) * 256 + tid;   // [0, NB*KP)
        int b = i >> 9;
        int n = i & (KP - 1);
        const float* r = R + b * 9;
        const float* t = T + b * 3;
        const float* s = skp + b * 3 * KP;
        const float* g = tkp + b * 3 * KP;
        float sx = s[n], sy = s[KP + n], sz = s[2 * KP + n];
        #pragma unroll
        for (int d = 0; d < 3; ++d) {
            float v = fmaf(r[d*3+0], sx, fmaf(r[d*3+1], sy, fmaf(r[d*3+2], sz, t[d])))
                      - g[d * KP + n];
            contrib = fmaf(v, v, contrib);
        }
        target = out;
    }

    // ---- block-wide sum -> single atomicAdd ----
    float v = contrib;
    #pragma unroll
    for (int off = 32; off; off >>= 1) v += __shfl_down(v, off, 64);
    if ((tid & 63) == 0) red[tid >> 6] = v;
    __syncthreads();
    if (tid == 0)
        atomicAdd(target, red[0] + red[1] + red[2] + red[3]);
}

// ---------------- launch ----------------

extern "C" void kernel_launch(void* const* d_in, const int* in_sizes, int n_in,
                              void* d_out, int out_size, void* d_ws, size_t ws_size,
                              hipStream_t stream) {
    const float* skp  = (const float*)d_in[0];   // (B,3,KP)
    const float* tkp  = (const float*)d_in[1];   // (B,3,KP)
    const float* R    = (const float*)d_in[2];   // (B,3,3)
    const float* T    = (const float*)d_in[3];   // (B,3)
    const float* aknn = (const float*)d_in[4];   // (B,3,KP,K)
    const float* bknn = (const float*)d_in[5];   // (B,3,KP,K)
    const int*   kptr = (const int*)d_in[6];     // scalar k
    const float* srcT = (const float*)d_in[7];   // (B,3,N)
    const float* tgtT = (const float*)d_in[8];   // (B,3,N)
    float* out = (float*)d_out;

    const int knn_quads  = in_sizes[4] / 4;                 // 49152
    const int knn_blocks = (knn_quads + 255) / 256;         // 192
    const int kp_blocks  = (NB * KP + 255) / 256;           // 8
    const int total      = GAL_BLOCKS + knn_blocks + kp_blocks;   // 456

    init_kernel<<<1, 64, 0, stream>>>(out);
    main_kernel<<<total, 256, 0, stream>>>(
        srcT, tgtT, skp, tkp, R, T, aknn, bknn, kptr, out,
        knn_blocks, knn_quads);
}